// Round 9
// baseline (33.030 us; speedup 1.0000x reference)
//
#include <hip/hip_runtime.h>

#define KS 21
#define CC 10
#define H 128
#define W 128
#define HW (H*W)
#define NCH 3
#define B 4
#define PW (W + 2*CC)   // 148
#define S 7             // i-row splits
#define CH 3            // i-rows per split

// kt: 63 rows x 152 f16 slots (value for px at slot px+12; slots 0..11 and
// 140..151 zero pads). Row stride 304 B. Tap (ii,j) e-read byte:
//   (ii*21+j)*304 + 2j + 4 + 2x
// dt: [CH][PW] of half4v {d0,d1,d2,0} (8 B/pixel). Tap data-read byte:
//   ii*1184 + (x+j)*8
#define KT_BYTES (63*304)            // 19152
#define DT_BYTES (CH*PW*8)           // 3552
typedef _Float16 half4v __attribute__((ext_vector_type(4)));

// grid (H, B, S), block 256. Block = one output row y, one 3-i-row chunk.
// Staging computes e=exp(g) once per kern element (f16, padded rows, e=0 for
// OOB); data tile packed f16. Compute is pure ds_read_u16+ds_read_b64+fma,
// j-split across block halves, fixed-order two-barrier combine. Deterministic.
__global__ __launch_bounds__(256, 6)
void kaw_part(const float* __restrict__ data,
              const float* __restrict__ kern,
              float4* __restrict__ part)
{
    __shared__ __align__(16) unsigned char smem[KT_BYTES + DT_BYTES];
    unsigned char* ktB = smem;
    unsigned char* dtB = smem + KT_BYTES;

    const int tid  = threadIdx.x;
    const int x    = tid & 127;
    const int half = tid >> 7;              // wave-uniform
    const int y  = blockIdx.x;
    const int b  = blockIdx.y;
    const int i0 = blockIdx.z * CH;

    const float* __restrict__ kbase = kern + (size_t)b * (KS * KS) * HW;
    const float* __restrict__ dbase = data + (size_t)b * NCH * HW;

    // ---- stage kern rows: e=exp(g) as f16. 63 rows x 32 quads ----
    #pragma unroll
    for (int k = 0; k < 8; ++k) {
        int idx = tid + k * 256;
        if (idx < 63 * 32) {
            int row = idx >> 5;             // 0..62 = ii*21 + j
            int c4  = idx & 31;
            int ii  = row >= 42 ? 2 : (row >= 21 ? 1 : 0);
            int j   = row - ii * 21;
            int q   = (KS - 1 - (i0 + ii)) * KS + (KS - 1 - j);
            int py  = y + i0 + ii - CC;
            half4v hv = (half4v){(_Float16)0, (_Float16)0, (_Float16)0, (_Float16)0};
            if ((unsigned)py < (unsigned)H) {
                float4 g = *reinterpret_cast<const float4*>(
                    kbase + (size_t)q * HW + (size_t)py * W + c4 * 4);
                hv = (half4v){(_Float16)__expf(g.x), (_Float16)__expf(g.y),
                              (_Float16)__expf(g.z), (_Float16)__expf(g.w)};
            }
            // value(px) at slot px+12: quad c4 -> bytes 24+8*c4 (8B aligned)
            *reinterpret_cast<half4v*>(ktB + row * 304 + 24 + c4 * 8) = hv;
        }
    }
    // zero the pads: slots 0..11 (bytes 0..23) and 140..151 (bytes 280..303)
    for (int p = tid; p < 63 * 12; p += 256) {
        int row = p / 12, k = p - row * 12;
        int off = row * 304 + (k < 6 ? k * 4 : 280 + (k - 6) * 4);
        *reinterpret_cast<unsigned*>(ktB + off) = 0u;
    }

    // ---- stage data rows: packed f16 {d0,d1,d2,0}, zero-filled OOB ----
    #pragma unroll
    for (int k = 0; k < 2; ++k) {
        int e = tid + k * 256;
        if (e < CH * PW) {
            int ii = e >= 2 * PW ? 2 : (e >= PW ? 1 : 0);
            int c  = e - ii * PW;
            int gy = y + i0 + ii - CC;
            int gx = c - CC;
            half4v v = (half4v){(_Float16)0, (_Float16)0, (_Float16)0, (_Float16)0};
            if ((unsigned)gy < (unsigned)H && (unsigned)gx < (unsigned)W) {
                v.x = (_Float16)dbase[(0 * H + gy) * W + gx];
                v.y = (_Float16)dbase[(1 * H + gy) * W + gx];
                v.z = (_Float16)dbase[(2 * H + gy) * W + gx];
            }
            *reinterpret_cast<half4v*>(dtB + e * 8) = v;
        }
    }
    __syncthreads();

    // ---- compute: half 0 -> j=0..10, half 1 -> j=11..20 (wave-uniform) ----
    float acc0 = 0.f, acc1 = 0.f, acc2 = 0.f, accw = 0.f;
    const int jb = half ? 11 : 0;
    const int nj = half ? 10 : 11;
    {
        const unsigned char* kp = ktB + 2 * x;   // + imm (ii*21+j)*304 + 2j + 4
        const unsigned char* dp = dtB + 8 * x;   // + imm ii*1184 + j*8
        #pragma unroll
        for (int ii = 0; ii < CH; ++ii) {
            #pragma unroll 11
            for (int jj = 0; jj < nj; ++jj) {
                const int j = jb + jj;
                _Float16 e16 = *reinterpret_cast<const _Float16*>(
                    kp + (ii * 21 + j) * 304 + 2 * j + 4);
                half4v dv = *reinterpret_cast<const half4v*>(
                    dp + ii * 1184 + j * 8);
                float e = (float)e16;
                acc0 += e * (float)dv.x;
                acc1 += e * (float)dv.y;
                acc2 += e * (float)dv.z;
                accw += e;
            }
        }
    }

    // ---- fixed-order combine: total = half0 + half1 ----
    __syncthreads();                         // kt/dt reads done; reuse dt as sred
    float* sred = (float*)dtB;               // 128*16 = 2048 <= 3552 B
    if (half == 1) {
        *reinterpret_cast<float4*>(sred + x * 4) = make_float4(acc0, acc1, acc2, accw);
    }
    __syncthreads();
    if (half == 0) {
        float4 s = *reinterpret_cast<const float4*>(sred + x * 4);
        acc0 += s.x; acc1 += s.y; acc2 += s.z; accw += s.w;
        part[(size_t)(blockIdx.z * B + b) * HW + (size_t)y * W + x] =
            make_float4(acc0, acc1, acc2, accw);
    }
}

// ---------- pass 2: fixed-order reduction + closed-form OOB denom + divide --
__global__ __launch_bounds__(256)
void kaw_reduce(const float4* __restrict__ part,
                float* __restrict__ out,
                float* __restrict__ sumw)
{
    const int idx = blockIdx.x * 256 + threadIdx.x;   // 0 .. B*HW-1
    const int b   = idx >> 14;
    const int px  = idx & (HW - 1);
    const int yy  = px >> 7;
    const int xx  = px & 127;

    float a0 = 0.f, a1 = 0.f, a2 = 0.f, aw = 0.f;
    #pragma unroll
    for (int s = 0; s < S; ++s) {
        float4 p = part[(size_t)(s * B + b) * HW + px];
        a0 += p.x;
        a1 += p.y;
        a2 += p.z;
        aw += p.w;
    }
    // OOB taps contribute exp(0)=1 each to the softmax denominator:
    // nry fully-OOB rows x 21, plus nrx OOB columns in each in-bounds row.
    int nry = max(0, CC - yy) + max(0, yy - (H - 1 - CC));
    int nrx = max(0, CC - xx) + max(0, xx - (W - 1 - CC));
    float cnt = 21.f * nry + (float)((21 - nry) * nrx);
    float inv = 1.0f / (aw + cnt);
    const size_t o = (size_t)b * NCH * HW + px;
    out[o]          = a0 * inv;
    out[o + HW]     = a1 * inv;
    out[o + 2 * HW] = a2 * inv;
    sumw[(size_t)b * HW + px] = aw * inv;
}

// ---------- fallback: proven monolithic kernel if ws too small --------------
#define TY 2
__global__ __launch_bounds__(256)
void kaw_mono(const float* __restrict__ data,
              const float* __restrict__ kern,
              float* __restrict__ out,
              float* __restrict__ sumw)
{
    const int x  = threadIdx.x;
    const int ty = threadIdx.y;
    const int y0 = blockIdx.x * TY;
    const int b  = blockIdx.y;
    const int y  = y0 + ty;

    __shared__ __align__(16) float sdat[TY + 2 * CC][PW][4];

    const float* __restrict__ dbase = data + (size_t)b * NCH * HW;
    const int tid = ty * W + x;
    for (int e = tid; e < (TY + 2 * CC) * PW; e += W * TY) {
        int r  = e / PW;
        int xx = e - r * PW;
        int gy = y0 + r - CC;
        int gx = xx - CC;
        float4 v = make_float4(0.f, 0.f, 0.f, 0.f);
        if ((unsigned)gy < (unsigned)H && (unsigned)gx < (unsigned)W) {
            v.x = dbase[(0 * H + gy) * W + gx];
            v.y = dbase[(1 * H + gy) * W + gx];
            v.z = dbase[(2 * H + gy) * W + gx];
        }
        *reinterpret_cast<float4*>(&sdat[r][xx][0]) = v;
    }
    __syncthreads();

    const float* __restrict__ kbase = kern + (size_t)b * (KS * KS) * HW;
    float acc0 = 0.f, acc1 = 0.f, acc2 = 0.f, accw = 0.f, accd = 0.f;

    for (int i = 0; i < KS; ++i) {
        const int py = y + i - CC;
        if ((unsigned)py >= (unsigned)H) { accd += (float)KS; continue; }
        const float* __restrict__ krow =
            kbase + (size_t)(KS - 1 - i) * KS * HW + (size_t)py * W;
        const float* __restrict__ srow = &sdat[ty + i][0][0];
        #pragma unroll
        for (int j = 0; j < KS; ++j) {
            int px = x + j - CC;
            bool vx = (unsigned)px < (unsigned)W;
            int spx = px < 0 ? 0 : (px > W - 1 ? W - 1 : px);
            float g = krow[(size_t)(KS - 1 - j) * HW + spx];
            float e = vx ? __expf(g) : 0.f;
            float4 dv = *reinterpret_cast<const float4*>(srow + (size_t)(x + j) * 4);
            acc0 += e * dv.x; acc1 += e * dv.y; acc2 += e * dv.z;
            accw += e; accd += vx ? e : 1.f;
        }
    }

    const float inv = 1.0f / accd;
    const size_t o = (size_t)b * NCH * HW + (size_t)y * W + x;
    out[o]          = acc0 * inv;
    out[o + HW]     = acc1 * inv;
    out[o + 2 * HW] = acc2 * inv;
    sumw[(size_t)b * HW + (size_t)y * W + x] = accw * inv;
}

extern "C" void kernel_launch(void* const* d_in, const int* in_sizes, int n_in,
                              void* d_out, int out_size, void* d_ws, size_t ws_size,
                              hipStream_t stream)
{
    const float* data = (const float*)d_in[0];   // (4,3,128,128) f32
    const float* kern = (const float*)d_in[1];   // (4,441,128,128) f32
    float* out  = (float*)d_out;                 // (4,3,128,128)
    float* sumw = out + (size_t)B * NCH * HW;    // (4,1,128,128)

    const size_t ws_need = (size_t)S * B * HW * sizeof(float4);  // ~7.3 MB
    if (ws_size >= ws_need) {
        float4* part = (float4*)d_ws;
        dim3 g1(H, B, S);
        kaw_part<<<g1, 256, 0, stream>>>(data, kern, part);
        kaw_reduce<<<B * HW / 256, 256, 0, stream>>>(part, out, sumw);
    } else {
        dim3 g(H / TY, B), blk(W, TY);
        kaw_mono<<<g, blk, 0, stream>>>(data, kern, out, sumw);
    }
}